// Round 3
// baseline (27300.623 us; speedup 1.0000x reference)
//
#include <hip/hip_runtime.h>

// Persistent 2-layer LSTM, PLAIN launch (grid=256=#CUs, 1 block/CU => all
// resident; custom device-scope grid barrier). Split-fp16 MFMA GEMMs
// (A*B ~= Ahi*Bhi + Alo*Bhi + Ahi*Blo, fp32 accum => ~22-bit mantissa),
// fp32 cell state / elementwise. WG (rb,cg): batch rows rb*64..+63, hidden
// units cg*8..+7 (32 gate cols). Pipelined: tick t = L1 step t + L2 step t-1;
// one grid barrier per tick.

#define WGS    256
#define NTHR   256
#define TSTEPS 512
#define HDIM   512
#define BATCH  256
#define FUT    8
#define NCOL   (TSTEPS + FUT)
#define HPLANE (BATCH * HDIM)   // elements in one (hi or lo) h plane

typedef _Float16 half_t;
typedef _Float16 f16x8 __attribute__((ext_vector_type(8)));
typedef float    f32x4 __attribute__((ext_vector_type(4)));

struct Params {
  const float* input_t;
  const float* W_ih1; const float* b_ih1; const float* W_hh1; const float* b_hh1;
  const float* W_ih2; const float* b_ih2; const float* W_hh2; const float* b_hh2;
  const float* W_lin; const float* b_lin;
  float* out;
  unsigned* barcnt; unsigned* bargen;
  float* outfeed;
  half_t* h1buf;   // [2 pp][2 hi/lo][BATCH][HDIM]
  half_t* h2buf;   // [2 pp][2 hi/lo][BATCH][HDIM]
};

__device__ __forceinline__ float sigm(float x)   { return 1.0f / (1.0f + expf(-x)); }
__device__ __forceinline__ float tanh_f(float x) { return tanhf(x); }

// fp32 row -> (hi, lo) fp16 fragments
__device__ __forceinline__ void load8_split(const float* p, f16x8& hi, f16x8& lo) {
  const float4 a = *(const float4*)p;
  const float4 b = *(const float4*)(p + 4);
  float v[8] = {a.x, a.y, a.z, a.w, b.x, b.y, b.z, b.w};
#pragma unroll
  for (int i = 0; i < 8; ++i) {
    const half_t h = (half_t)v[i];
    hi[i] = h;
    lo[i] = (half_t)(v[i] - (float)h);
  }
}

// Sense-reversing grid barrier (monotonic count, generation word).
__device__ __forceinline__ void gridbar(unsigned* cnt, unsigned* gen, unsigned bid) {
  __syncthreads();
  if (threadIdx.x == 0) {
    __threadfence();  // publish h writes device-wide
    unsigned arrived =
        __hip_atomic_fetch_add(cnt, 1u, __ATOMIC_ACQ_REL, __HIP_MEMORY_SCOPE_AGENT) + 1u;
    const unsigned want = (bid + 1u) * (unsigned)WGS;
    if (arrived == want) {
      __hip_atomic_store(gen, bid + 1u, __ATOMIC_RELEASE, __HIP_MEMORY_SCOPE_AGENT);
    } else {
      unsigned iters = 0;
      while (__hip_atomic_load(gen, __ATOMIC_ACQUIRE, __HIP_MEMORY_SCOPE_AGENT) < bid + 1u) {
        __builtin_amdgcn_s_sleep(1);
        if (++iters > 100000000u) break;  // failsafe: ~2-3 s, prevents suite hang
      }
    }
  }
  __syncthreads();
}

__global__ void __launch_bounds__(NTHR, 1) lstm_fused(Params P) {
  const int tid  = threadIdx.x;
  const int wg   = blockIdx.x;
  const int cg   = wg & 63;    // unit group: hidden units cg*8 .. +7
  const int rb   = wg >> 6;    // row block: batch rows rb*64 .. +63
  const int wv   = tid >> 6;   // wave 0..3
  const int lane = tid & 63;
  const int rh   = wv >> 1;    // row half (32 rows)
  const int cc   = wv & 1;     // col half (16 of 32 gate cols)
  const int m    = lane & 15;
  const int quad = lane >> 4;

  __shared__ float g1s[64 * 33];          // L1 gate pre-acts [row][p]
  __shared__ float g2s[64 * 33];          // L2 gate pre-acts
  __shared__ f16x8 b1lo_s[2][16][64];     // W_hh1 lo fragments, per cc (32 KB)
  __shared__ float in_s[64];
  __shared__ float bias1_s[32];
  __shared__ float w1x_s[32];
  __shared__ float bias2_s[32];

  if (tid < 32) {
    const int gate = tid >> 3, ul = tid & 7;
    const int gc = gate * HDIM + cg * 8 + ul;
    bias1_s[tid] = P.b_ih1[gc] + P.b_hh1[gc];
    w1x_s[tid]   = P.W_ih1[gc];
    bias2_s[tid] = P.b_ih2[gc] + P.b_hh2[gc];
  }
  if (tid < 64) in_s[tid] = P.input_t[rb * 64 + tid];

  // Register-resident fp16 B fragments (hi for all, lo for W_ih2/W_hh2;
  // W_hh1 lo lives in LDS to stay under the VGPR spill threshold).
  // mfma_f32_16x16x32_f16 B layout: lane L holds B[k=(L>>4)*8+j][n=L&15].
  f16x8 B1h[16];    // W_hh1 hi
  f16x8 B2h[32];    // [0..15]=W_ih2 hi, [16..31]=W_hh2 hi
  f16x8 B2l[32];    // lo parts of W_ih2 / W_hh2
  {
    const int pcol = cc * 16 + m;
    const int gate = pcol >> 3, ul = pcol & 7;
    const int gc = gate * HDIM + cg * 8 + ul;
    const float* w1r  = P.W_hh1 + (size_t)gc * HDIM;
    const float* wi2r = P.W_ih2 + (size_t)gc * HDIM;
    const float* wh2r = P.W_hh2 + (size_t)gc * HDIM;
#pragma unroll
    for (int kk = 0; kk < 16; ++kk) {
      const int k0 = kk * 32 + quad * 8;
      f16x8 lo1;
      load8_split(w1r + k0, B1h[kk], lo1);
      load8_split(wi2r + k0, B2h[kk], B2l[kk]);
      load8_split(wh2r + k0, B2h[16 + kk], B2l[16 + kk]);
      if (wv < 2) b1lo_s[cc][kk][lane] = lo1;   // waves 0/1 cover cc 0/1
    }
  }
  __syncthreads();

  float c1[2] = {0.f, 0.f}, c2[2] = {0.f, 0.f};   // cell state (fp32, registers)
  const int eb  = tid >> 2;        // elementwise: batch row 0..63
  const int eu0 = (tid & 3) * 2;   // elementwise: first of 2 units

  // Output row: WG wg handles batch row wg (independent of its GEMM role).
  auto outrow = [&](const half_t* h2p, int col) {
    if (tid < 64) {
      const f16x8 hv = *(const f16x8*)(h2p + (size_t)wg * HDIM + lane * 8);
      const f16x8 hl = *(const f16x8*)(h2p + HPLANE + (size_t)wg * HDIM + lane * 8);
      const float4 wa = *(const float4*)(P.W_lin + lane * 8);
      const float4 wb = *(const float4*)(P.W_lin + lane * 8 + 4);
      float s = ((float)hv[0] + (float)hl[0]) * wa.x + ((float)hv[1] + (float)hl[1]) * wa.y
              + ((float)hv[2] + (float)hl[2]) * wa.z + ((float)hv[3] + (float)hl[3]) * wa.w
              + ((float)hv[4] + (float)hl[4]) * wb.x + ((float)hv[5] + (float)hl[5]) * wb.y
              + ((float)hv[6] + (float)hl[6]) * wb.z + ((float)hv[7] + (float)hl[7]) * wb.w;
#pragma unroll
      for (int off = 32; off > 0; off >>= 1) s += __shfl_down(s, off);
      if (lane == 0) {
        s += P.b_lin[0];
        P.out[(size_t)wg * NCOL + col] = s;
        P.outfeed[wg] = s;
      }
    }
  };

  auto tick = [&](bool doL1, bool doL2, bool doOUT, bool future, int outcol,
                  const half_t* h1rp, half_t* h1wp,
                  const half_t* h2rp, half_t* h2wp) {
    if (doOUT) outrow(h2rp, outcol);   // out[t-2] from h2[t-2]

    const f32x4 z4 = {0.f, 0.f, 0.f, 0.f};
    f32x4 acc1[2] = {z4, z4};
    f32x4 acc2[2] = {z4, z4};

    // A layout: lane L holds A[m=L&15][k=(L>>4)*8+j]
    const half_t* a1 = h1rp + (size_t)(rb * 64 + rh * 32 + m) * HDIM;
    const half_t* a2 = h2rp + (size_t)(rb * 64 + rh * 32 + m) * HDIM;
    const int koff = quad * 8;

#pragma unroll
    for (int kk = 0; kk < 16; ++kk) {   // k 0..511 : A = h1[t-1] (L1 & L2-x)
      if (doL1 | doL2) {
        const int o = kk * 32 + koff;
        const f16x8 a0h = *(const f16x8*)(a1 + o);
        const f16x8 a1h = *(const f16x8*)(a1 + 16 * HDIM + o);
        const f16x8 a0l = *(const f16x8*)(a1 + HPLANE + o);
        const f16x8 a1l = *(const f16x8*)(a1 + HPLANE + 16 * HDIM + o);
        if (doL1) {
          const f16x8 bl1 = b1lo_s[cc][kk][lane];
          acc1[0] = __builtin_amdgcn_mfma_f32_16x16x32_f16(a0h, B1h[kk], acc1[0], 0, 0, 0);
          acc1[1] = __builtin_amdgcn_mfma_f32_16x16x32_f16(a1h, B1h[kk], acc1[1], 0, 0, 0);
          acc1[0] = __builtin_amdgcn_mfma_f32_16x16x32_f16(a0l, B1h[kk], acc1[0], 0, 0, 0);
          acc1[1] = __builtin_amdgcn_mfma_f32_16x16x32_f16(a1l, B1h[kk], acc1[1], 0, 0, 0);
          acc1[0] = __builtin_amdgcn_mfma_f32_16x16x32_f16(a0h, bl1, acc1[0], 0, 0, 0);
          acc1[1] = __builtin_amdgcn_mfma_f32_16x16x32_f16(a1h, bl1, acc1[1], 0, 0, 0);
        }
        if (doL2) {
          acc2[0] = __builtin_amdgcn_mfma_f32_16x16x32_f16(a0h, B2h[kk], acc2[0], 0, 0, 0);
          acc2[1] = __builtin_amdgcn_mfma_f32_16x16x32_f16(a1h, B2h[kk], acc2[1], 0, 0, 0);
          acc2[0] = __builtin_amdgcn_mfma_f32_16x16x32_f16(a0l, B2h[kk], acc2[0], 0, 0, 0);
          acc2[1] = __builtin_amdgcn_mfma_f32_16x16x32_f16(a1l, B2h[kk], acc2[1], 0, 0, 0);
          acc2[0] = __builtin_amdgcn_mfma_f32_16x16x32_f16(a0h, B2l[kk], acc2[0], 0, 0, 0);
          acc2[1] = __builtin_amdgcn_mfma_f32_16x16x32_f16(a1h, B2l[kk], acc2[1], 0, 0, 0);
        }
      }
    }
#pragma unroll
    for (int kk = 0; kk < 16; ++kk) {   // k 512..1023 : A = h2[t-2] (L2 hidden)
      if (doL2) {
        const int o = kk * 32 + koff;
        const f16x8 a0h = *(const f16x8*)(a2 + o);
        const f16x8 a1h = *(const f16x8*)(a2 + 16 * HDIM + o);
        const f16x8 a0l = *(const f16x8*)(a2 + HPLANE + o);
        const f16x8 a1l = *(const f16x8*)(a2 + HPLANE + 16 * HDIM + o);
        acc2[0] = __builtin_amdgcn_mfma_f32_16x16x32_f16(a0h, B2h[16 + kk], acc2[0], 0, 0, 0);
        acc2[1] = __builtin_amdgcn_mfma_f32_16x16x32_f16(a1h, B2h[16 + kk], acc2[1], 0, 0, 0);
        acc2[0] = __builtin_amdgcn_mfma_f32_16x16x32_f16(a0l, B2h[16 + kk], acc2[0], 0, 0, 0);
        acc2[1] = __builtin_amdgcn_mfma_f32_16x16x32_f16(a1l, B2h[16 + kk], acc2[1], 0, 0, 0);
        acc2[0] = __builtin_amdgcn_mfma_f32_16x16x32_f16(a0h, B2l[16 + kk], acc2[0], 0, 0, 0);
        acc2[1] = __builtin_amdgcn_mfma_f32_16x16x32_f16(a1h, B2l[16 + kk], acc2[1], 0, 0, 0);
      }
    }

    // C/D layout: col = lane&15, row = (lane>>4)*4 + reg
    if (doL1) {
#pragma unroll
      for (int rt = 0; rt < 2; ++rt)
#pragma unroll
        for (int rg = 0; rg < 4; ++rg)
          g1s[(rh * 32 + rt * 16 + quad * 4 + rg) * 33 + cc * 16 + m] = acc1[rt][rg];
    }
    if (doL2) {
#pragma unroll
      for (int rt = 0; rt < 2; ++rt)
#pragma unroll
        for (int rg = 0; rg < 4; ++rg)
          g2s[(rh * 32 + rt * 16 + quad * 4 + rg) * 33 + cc * 16 + m] = acc2[rt][rg];
    }
    __syncthreads();

    // Elementwise: thread owns 2 (b,u) pairs; c-state stays in registers.
    float xb = 0.f;
    if (doL1) xb = future ? P.outfeed[rb * 64 + eb] : in_s[eb];
#pragma unroll
    for (int uu = 0; uu < 2; ++uu) {
      const int u = eu0 + uu;
      if (doL1) {
        const float ai = g1s[eb * 33 + u]      + xb * w1x_s[u]      + bias1_s[u];
        const float af = g1s[eb * 33 + 8 + u]  + xb * w1x_s[8 + u]  + bias1_s[8 + u];
        const float ag = g1s[eb * 33 + 16 + u] + xb * w1x_s[16 + u] + bias1_s[16 + u];
        const float ao = g1s[eb * 33 + 24 + u] + xb * w1x_s[24 + u] + bias1_s[24 + u];
        const float ig = sigm(ai), fg = sigm(af), gg = tanh_f(ag), og = sigm(ao);
        const float c = fg * c1[uu] + ig * gg;
        c1[uu] = c;
        const float h = og * tanh_f(c);
        const half_t hh = (half_t)h;
        const size_t idx = (size_t)(rb * 64 + eb) * HDIM + cg * 8 + u;
        h1wp[idx] = hh;
        h1wp[HPLANE + idx] = (half_t)(h - (float)hh);
      }
      if (doL2) {
        const float ai = g2s[eb * 33 + u]      + bias2_s[u];
        const float af = g2s[eb * 33 + 8 + u]  + bias2_s[8 + u];
        const float ag = g2s[eb * 33 + 16 + u] + bias2_s[16 + u];
        const float ao = g2s[eb * 33 + 24 + u] + bias2_s[24 + u];
        const float ig = sigm(ai), fg = sigm(af), gg = tanh_f(ag), og = sigm(ao);
        const float c = fg * c2[uu] + ig * gg;
        c2[uu] = c;
        const float h = og * tanh_f(c);
        const half_t hh = (half_t)h;
        const size_t idx = (size_t)(rb * 64 + eb) * HDIM + cg * 8 + u;
        h2wp[idx] = hh;
        h2wp[HPLANE + idx] = (half_t)(h - (float)hh);
      }
    }
  };

  half_t* h1b0 = P.h1buf;  half_t* h1b1 = P.h1buf + 2 * HPLANE;
  half_t* h2b0 = P.h2buf;  half_t* h2b1 = P.h2buf + 2 * HPLANE;

  unsigned bid = 0;
  // Main pipelined ticks: tick t = L1 step t, L2 step t-1, OUT step t-2.
  // h1[s] lives in h1buf[s&1]; h2[s] in h2buf[s&1]. Buffers pre-zeroed.
  for (int t = 0; t <= TSTEPS; ++t) {
    half_t* h1r = ((t + 1) & 1) ? h1b1 : h1b0;   // h1[t-1]
    half_t* h1w = (t & 1)       ? h1b1 : h1b0;   // h1[t]
    half_t* h2r = (t & 1)       ? h2b1 : h2b0;   // h2[t-2]
    half_t* h2w = ((t + 1) & 1) ? h2b1 : h2b0;   // h2[t-1]
    tick(t < TSTEPS, t >= 1, t >= 2, false, t - 2, h1r, h1w, h2r, h2w);
    gridbar(P.barcnt, P.bargen, bid++);
  }
  // Autoregressive future steps: out feeds back => 3 phases each.
  for (int k = 0; k < FUT; ++k) {
    const int s = TSTEPS + k;
    const half_t* h2last = (((s - 1) & 1)) ? h2b1 : h2b0;  // h2[s-1]
    outrow(h2last, s - 1);
    gridbar(P.barcnt, P.bargen, bid++);
    {  // L1 future step s (x = outfeed)
      half_t* h1r = (((s - 1) & 1)) ? h1b1 : h1b0;
      half_t* h1w = ((s & 1))       ? h1b1 : h1b0;
      tick(true, false, false, true, 0, h1r, h1w, h2b0, h2b0);
      gridbar(P.barcnt, P.bargen, bid++);
    }
    {  // L2 future step s (x = h1[s], hidden = h2[s-1])
      half_t* h1r = ((s & 1))       ? h1b1 : h1b0;
      half_t* h2r = (((s - 1) & 1)) ? h2b1 : h2b0;
      half_t* h2w = ((s & 1))       ? h2b1 : h2b0;
      tick(false, true, false, false, 0, h1r, h1b0, h2r, h2w);
      gridbar(P.barcnt, P.bargen, bid++);
    }
  }
  outrow((((TSTEPS + 7) & 1)) ? h2b1 : h2b0, TSTEPS + 7);
}

extern "C" void kernel_launch(void* const* d_in, const int* in_sizes, int n_in,
                              void* d_out, int out_size, void* d_ws, size_t ws_size,
                              hipStream_t stream) {
  Params P;
  P.input_t = (const float*)d_in[0];
  // d_in[1] = y : only its shape (T) matters; T hardcoded 512
  P.W_ih1 = (const float*)d_in[2];  P.b_ih1 = (const float*)d_in[3];
  P.W_hh1 = (const float*)d_in[4];  P.b_hh1 = (const float*)d_in[5];
  P.W_ih2 = (const float*)d_in[6];  P.b_ih2 = (const float*)d_in[7];
  P.W_hh2 = (const float*)d_in[8];  P.b_hh2 = (const float*)d_in[9];
  P.W_lin = (const float*)d_in[10]; P.b_lin = (const float*)d_in[11];
  P.out   = (float*)d_out;

  char* ws = (char*)d_ws;
  P.barcnt  = (unsigned*)(ws + 0);
  P.bargen  = (unsigned*)(ws + 64);
  P.outfeed = (float*)(ws + 256);
  P.h1buf   = (half_t*)(ws + 2048);                                   // [2][2][B][H]
  P.h2buf   = (half_t*)(ws + 2048 + 4 * (size_t)HPLANE * sizeof(half_t));
  const size_t need = 2048 + 8 * (size_t)HPLANE * sizeof(half_t);     // ~2.1 MB

  hipMemsetAsync(d_ws, 0, need, stream);  // zero barrier block + h buffers

  // PLAIN launch: grid == 256 CUs, 1 block/CU by resources => all resident.
  // (hipLaunchCooperativeKernel silently failed under this harness; our own
  //  device-scope barrier provides the grid sync.)
  lstm_fused<<<dim3(WGS), dim3(NTHR), 0, stream>>>(P);
}

// Round 5
// 15192.224 us; speedup vs baseline: 1.7970x; 1.7970x over previous
//
#include <hip/hip_runtime.h>

// Persistent 2-layer LSTM, plain launch (grid=256=#CUs, 1 block/CU => all
// resident). Split-fp16 MFMA GEMMs (A*B ~= Ahi*Bhi + Alo*Bhi + Ahi*Blo, fp32
// accum => ~22-bit mantissa), fp32 cell state / elementwise.
// WG (rb,cg): batch rows rb*64..+63, hidden units cg*8..+7 (32 gate cols).
// Pipelined: tick t = L1 step t + L2 step t-1; one barrier per tick.
// Barrier: store-based per-WG flags, 4 independent 64-WG group barriers
// (group rb is fully self-contained: h rows, outfeed, out are all intra-group).

#define WGS    256
#define NTHR   256
#define TSTEPS 512
#define HDIM   512
#define BATCH  256
#define FUT    8
#define NCOL   (TSTEPS + FUT)
#define HPLANE (BATCH * HDIM)   // elements in one (hi or lo) h plane
#define FLAGSTRIDE 32           // u32s per flag line (128 B padding)

typedef _Float16 half_t;
typedef _Float16 f16x8 __attribute__((ext_vector_type(8)));
typedef float    f32x4 __attribute__((ext_vector_type(4)));

struct Params {
  const float* input_t;
  const float* W_ih1; const float* b_ih1; const float* W_hh1; const float* b_hh1;
  const float* W_ih2; const float* b_ih2; const float* W_hh2; const float* b_hh2;
  const float* W_lin; const float* b_lin;
  float* out;
  unsigned* flags;     // [WGS][FLAGSTRIDE]
  float* outfeed;
  half_t* h1buf;   // [2 pp][2 hi/lo][BATCH][HDIM]
  half_t* h2buf;   // [2 pp][2 hi/lo][BATCH][HDIM]
};

__device__ __forceinline__ float sigm(float x)   { return 1.0f / (1.0f + expf(-x)); }
__device__ __forceinline__ float tanh_f(float x) { return tanhf(x); }

// fp32 row -> (hi, lo) fp16 fragments
__device__ __forceinline__ void load8_split(const float* p, f16x8& hi, f16x8& lo) {
  const float4 a = *(const float4*)p;
  const float4 b = *(const float4*)(p + 4);
  float v[8] = {a.x, a.y, a.z, a.w, b.x, b.y, b.z, b.w};
#pragma unroll
  for (int i = 0; i < 8; ++i) {
    const half_t h = (half_t)v[i];
    hi[i] = h;
    lo[i] = (half_t)(v[i] - (float)h);
  }
}

// Group barrier (64 WGs sharing rb). Store-release own flag (parallel, no RMW);
// wave 0 polls the group's 64 flags with relaxed loads; one acquire fence.
__device__ __forceinline__ void groupbar(unsigned* flags, int rb, int wg, unsigned target) {
  __syncthreads();   // all waves' h stores drained (vmcnt(0) before s_barrier)
  if (threadIdx.x == 0) {
    __builtin_amdgcn_fence(__ATOMIC_RELEASE, "agent");  // wb dirty L2
    __hip_atomic_store(&flags[wg * FLAGSTRIDE], target,
                       __ATOMIC_RELAXED, __HIP_MEMORY_SCOPE_AGENT);
  }
  if (threadIdx.x < 64) {
    unsigned iters = 0;
    while (__hip_atomic_load(&flags[(rb * 64 + threadIdx.x) * FLAGSTRIDE],
                             __ATOMIC_RELAXED, __HIP_MEMORY_SCOPE_AGENT) < target) {
      __builtin_amdgcn_s_sleep(1);
      if (++iters > 5000000u) break;  // failsafe ~2 s, prevents suite hang
    }
  }
  if (threadIdx.x == 0)
    __builtin_amdgcn_fence(__ATOMIC_ACQUIRE, "agent");  // inv L1/L2
  __syncthreads();
}

__global__ void __launch_bounds__(NTHR, 1) lstm_fused(Params P) {
  const int tid  = threadIdx.x;
  const int wg   = blockIdx.x;
  const int cg   = wg & 63;    // unit group: hidden units cg*8 .. +7
  const int rb   = wg >> 6;    // row block: batch rows rb*64 .. +63
  const int wv   = tid >> 6;   // wave 0..3
  const int lane = tid & 63;
  const int rh   = wv >> 1;    // row half (32 rows)
  const int cc   = wv & 1;     // col half (16 of 32 gate cols)
  const int m    = lane & 15;
  const int quad = lane >> 4;

  __shared__ float g1s[64 * 33];          // L1 gate pre-acts [row][p]
  __shared__ float g2s[64 * 33];          // L2 gate pre-acts
  __shared__ f16x8 b1lo_s[2][16][64];     // W_hh1 lo fragments, per cc (32 KB)
  __shared__ float in_s[64];
  __shared__ float bias1_s[32];
  __shared__ float w1x_s[32];
  __shared__ float bias2_s[32];

  if (tid < 32) {
    const int gate = tid >> 3, ul = tid & 7;
    const int gc = gate * HDIM + cg * 8 + ul;
    bias1_s[tid] = P.b_ih1[gc] + P.b_hh1[gc];
    w1x_s[tid]   = P.W_ih1[gc];
    bias2_s[tid] = P.b_ih2[gc] + P.b_hh2[gc];
  }
  if (tid < 64) in_s[tid] = P.input_t[rb * 64 + tid];

  // Register-resident fp16 B fragments (hi for all, lo for W_ih2/W_hh2;
  // W_hh1 lo lives in LDS to stay under the VGPR spill threshold).
  // mfma_f32_16x16x32_f16 B layout: lane L holds B[k=(L>>4)*8+j][n=L&15].
  f16x8 B1h[16];    // W_hh1 hi
  f16x8 B2h[32];    // [0..15]=W_ih2 hi, [16..31]=W_hh2 hi
  f16x8 B2l[32];    // lo parts of W_ih2 / W_hh2
  {
    const int pcol = cc * 16 + m;
    const int gate = pcol >> 3, ul = pcol & 7;
    const int gc = gate * HDIM + cg * 8 + ul;
    const float* w1r  = P.W_hh1 + (size_t)gc * HDIM;
    const float* wi2r = P.W_ih2 + (size_t)gc * HDIM;
    const float* wh2r = P.W_hh2 + (size_t)gc * HDIM;
#pragma unroll
    for (int kk = 0; kk < 16; ++kk) {
      const int k0 = kk * 32 + quad * 8;
      f16x8 lo1;
      load8_split(w1r + k0, B1h[kk], lo1);
      load8_split(wi2r + k0, B2h[kk], B2l[kk]);
      load8_split(wh2r + k0, B2h[16 + kk], B2l[16 + kk]);
      if (wv < 2) b1lo_s[cc][kk][lane] = lo1;   // waves 0/1 cover cc 0/1
    }
  }
  __syncthreads();

  float c1[2] = {0.f, 0.f}, c2[2] = {0.f, 0.f};   // cell state (fp32, registers)
  const int eb  = tid >> 2;        // elementwise: batch row 0..63
  const int eu0 = (tid & 3) * 2;   // elementwise: first of 2 units

  // Output row: WG wg handles batch row wg (row wg is in its own rb group).
  auto outrow = [&](const half_t* h2p, int col) {
    if (tid < 64) {
      const f16x8 hv = *(const f16x8*)(h2p + (size_t)wg * HDIM + lane * 8);
      const f16x8 hl = *(const f16x8*)(h2p + HPLANE + (size_t)wg * HDIM + lane * 8);
      const float4 wa = *(const float4*)(P.W_lin + lane * 8);
      const float4 wb = *(const float4*)(P.W_lin + lane * 8 + 4);
      float s = ((float)hv[0] + (float)hl[0]) * wa.x + ((float)hv[1] + (float)hl[1]) * wa.y
              + ((float)hv[2] + (float)hl[2]) * wa.z + ((float)hv[3] + (float)hl[3]) * wa.w
              + ((float)hv[4] + (float)hl[4]) * wb.x + ((float)hv[5] + (float)hl[5]) * wb.y
              + ((float)hv[6] + (float)hl[6]) * wb.z + ((float)hv[7] + (float)hl[7]) * wb.w;
#pragma unroll
      for (int off = 32; off > 0; off >>= 1) s += __shfl_down(s, off);
      if (lane == 0) {
        s += P.b_lin[0];
        P.out[(size_t)wg * NCOL + col] = s;
        P.outfeed[wg] = s;
      }
    }
  };

  auto tick = [&](bool doL1, bool doL2, bool doOUT, bool future, int outcol,
                  const half_t* h1rp, half_t* h1wp,
                  const half_t* h2rp, half_t* h2wp) {
    if (doOUT) outrow(h2rp, outcol);   // out[t-2] from h2[t-2]

    const f32x4 z4 = {0.f, 0.f, 0.f, 0.f};
    f32x4 acc1[2] = {z4, z4};
    f32x4 acc2[2] = {z4, z4};

    // A layout: lane L holds A[m=L&15][k=(L>>4)*8+j]
    const half_t* a1 = h1rp + (size_t)(rb * 64 + rh * 32 + m) * HDIM;
    const half_t* a2 = h2rp + (size_t)(rb * 64 + rh * 32 + m) * HDIM;
    const int koff = quad * 8;

#pragma unroll
    for (int kk = 0; kk < 16; ++kk) {   // k 0..511 : A = h1[t-1] (L1 & L2-x)
      if (doL1 | doL2) {
        const int o = kk * 32 + koff;
        const f16x8 a0h = *(const f16x8*)(a1 + o);
        const f16x8 a1h = *(const f16x8*)(a1 + 16 * HDIM + o);
        const f16x8 a0l = *(const f16x8*)(a1 + HPLANE + o);
        const f16x8 a1l = *(const f16x8*)(a1 + HPLANE + 16 * HDIM + o);
        if (doL1) {
          const f16x8 bl1 = b1lo_s[cc][kk][lane];
          acc1[0] = __builtin_amdgcn_mfma_f32_16x16x32_f16(a0h, B1h[kk], acc1[0], 0, 0, 0);
          acc1[1] = __builtin_amdgcn_mfma_f32_16x16x32_f16(a1h, B1h[kk], acc1[1], 0, 0, 0);
          acc1[0] = __builtin_amdgcn_mfma_f32_16x16x32_f16(a0l, B1h[kk], acc1[0], 0, 0, 0);
          acc1[1] = __builtin_amdgcn_mfma_f32_16x16x32_f16(a1l, B1h[kk], acc1[1], 0, 0, 0);
          acc1[0] = __builtin_amdgcn_mfma_f32_16x16x32_f16(a0h, bl1, acc1[0], 0, 0, 0);
          acc1[1] = __builtin_amdgcn_mfma_f32_16x16x32_f16(a1h, bl1, acc1[1], 0, 0, 0);
        }
        if (doL2) {
          acc2[0] = __builtin_amdgcn_mfma_f32_16x16x32_f16(a0h, B2h[kk], acc2[0], 0, 0, 0);
          acc2[1] = __builtin_amdgcn_mfma_f32_16x16x32_f16(a1h, B2h[kk], acc2[1], 0, 0, 0);
          acc2[0] = __builtin_amdgcn_mfma_f32_16x16x32_f16(a0l, B2h[kk], acc2[0], 0, 0, 0);
          acc2[1] = __builtin_amdgcn_mfma_f32_16x16x32_f16(a1l, B2h[kk], acc2[1], 0, 0, 0);
          acc2[0] = __builtin_amdgcn_mfma_f32_16x16x32_f16(a0h, B2l[kk], acc2[0], 0, 0, 0);
          acc2[1] = __builtin_amdgcn_mfma_f32_16x16x32_f16(a1h, B2l[kk], acc2[1], 0, 0, 0);
        }
      }
    }
#pragma unroll
    for (int kk = 0; kk < 16; ++kk) {   // k 512..1023 : A = h2[t-2] (L2 hidden)
      if (doL2) {
        const int o = kk * 32 + koff;
        const f16x8 a0h = *(const f16x8*)(a2 + o);
        const f16x8 a1h = *(const f16x8*)(a2 + 16 * HDIM + o);
        const f16x8 a0l = *(const f16x8*)(a2 + HPLANE + o);
        const f16x8 a1l = *(const f16x8*)(a2 + HPLANE + 16 * HDIM + o);
        acc2[0] = __builtin_amdgcn_mfma_f32_16x16x32_f16(a0h, B2h[16 + kk], acc2[0], 0, 0, 0);
        acc2[1] = __builtin_amdgcn_mfma_f32_16x16x32_f16(a1h, B2h[16 + kk], acc2[1], 0, 0, 0);
        acc2[0] = __builtin_amdgcn_mfma_f32_16x16x32_f16(a0l, B2h[16 + kk], acc2[0], 0, 0, 0);
        acc2[1] = __builtin_amdgcn_mfma_f32_16x16x32_f16(a1l, B2h[16 + kk], acc2[1], 0, 0, 0);
        acc2[0] = __builtin_amdgcn_mfma_f32_16x16x32_f16(a0h, B2l[16 + kk], acc2[0], 0, 0, 0);
        acc2[1] = __builtin_amdgcn_mfma_f32_16x16x32_f16(a1h, B2l[16 + kk], acc2[1], 0, 0, 0);
      }
    }

    // C/D layout: col = lane&15, row = (lane>>4)*4 + reg
    if (doL1) {
#pragma unroll
      for (int rt = 0; rt < 2; ++rt)
#pragma unroll
        for (int rg = 0; rg < 4; ++rg)
          g1s[(rh * 32 + rt * 16 + quad * 4 + rg) * 33 + cc * 16 + m] = acc1[rt][rg];
    }
    if (doL2) {
#pragma unroll
      for (int rt = 0; rt < 2; ++rt)
#pragma unroll
        for (int rg = 0; rg < 4; ++rg)
          g2s[(rh * 32 + rt * 16 + quad * 4 + rg) * 33 + cc * 16 + m] = acc2[rt][rg];
    }
    __syncthreads();

    // Elementwise: thread owns 2 (b,u) pairs; c-state stays in registers.
    float xb = 0.f;
    if (doL1) xb = future ? P.outfeed[rb * 64 + eb] : in_s[eb];
#pragma unroll
    for (int uu = 0; uu < 2; ++uu) {
      const int u = eu0 + uu;
      if (doL1) {
        const float ai = g1s[eb * 33 + u]      + xb * w1x_s[u]      + bias1_s[u];
        const float af = g1s[eb * 33 + 8 + u]  + xb * w1x_s[8 + u]  + bias1_s[8 + u];
        const float ag = g1s[eb * 33 + 16 + u] + xb * w1x_s[16 + u] + bias1_s[16 + u];
        const float ao = g1s[eb * 33 + 24 + u] + xb * w1x_s[24 + u] + bias1_s[24 + u];
        const float ig = sigm(ai), fg = sigm(af), gg = tanh_f(ag), og = sigm(ao);
        const float c = fg * c1[uu] + ig * gg;
        c1[uu] = c;
        const float h = og * tanh_f(c);
        const half_t hh = (half_t)h;
        const size_t idx = (size_t)(rb * 64 + eb) * HDIM + cg * 8 + u;
        h1wp[idx] = hh;
        h1wp[HPLANE + idx] = (half_t)(h - (float)hh);
      }
      if (doL2) {
        const float ai = g2s[eb * 33 + u]      + bias2_s[u];
        const float af = g2s[eb * 33 + 8 + u]  + bias2_s[8 + u];
        const float ag = g2s[eb * 33 + 16 + u] + bias2_s[16 + u];
        const float ao = g2s[eb * 33 + 24 + u] + bias2_s[24 + u];
        const float ig = sigm(ai), fg = sigm(af), gg = tanh_f(ag), og = sigm(ao);
        const float c = fg * c2[uu] + ig * gg;
        c2[uu] = c;
        const float h = og * tanh_f(c);
        const half_t hh = (half_t)h;
        const size_t idx = (size_t)(rb * 64 + eb) * HDIM + cg * 8 + u;
        h2wp[idx] = hh;
        h2wp[HPLANE + idx] = (half_t)(h - (float)hh);
      }
    }
  };

  half_t* h1b0 = P.h1buf;  half_t* h1b1 = P.h1buf + 2 * HPLANE;
  half_t* h2b0 = P.h2buf;  half_t* h2b1 = P.h2buf + 2 * HPLANE;

  unsigned bid = 0;
  // Main pipelined ticks: tick t = L1 step t, L2 step t-1, OUT step t-2.
  // h1[s] lives in h1buf[s&1]; h2[s] in h2buf[s&1]. Buffers pre-zeroed.
  for (int t = 0; t <= TSTEPS; ++t) {
    half_t* h1r = ((t + 1) & 1) ? h1b1 : h1b0;   // h1[t-1]
    half_t* h1w = (t & 1)       ? h1b1 : h1b0;   // h1[t]
    half_t* h2r = (t & 1)       ? h2b1 : h2b0;   // h2[t-2]
    half_t* h2w = ((t + 1) & 1) ? h2b1 : h2b0;   // h2[t-1]
    tick(t < TSTEPS, t >= 1, t >= 2, false, t - 2, h1r, h1w, h2r, h2w);
    groupbar(P.flags, rb, wg, ++bid);
  }
  // Autoregressive future steps: out feeds back => 3 phases each.
  for (int k = 0; k < FUT; ++k) {
    const int s = TSTEPS + k;
    const half_t* h2last = (((s - 1) & 1)) ? h2b1 : h2b0;  // h2[s-1]
    outrow(h2last, s - 1);
    groupbar(P.flags, rb, wg, ++bid);
    {  // L1 future step s (x = outfeed)
      half_t* h1r = (((s - 1) & 1)) ? h1b1 : h1b0;
      half_t* h1w = ((s & 1))       ? h1b1 : h1b0;
      tick(true, false, false, true, 0, h1r, h1w, h2b0, h2b0);
      groupbar(P.flags, rb, wg, ++bid);
    }
    {  // L2 future step s (x = h1[s], hidden = h2[s-1])
      half_t* h1r = ((s & 1))       ? h1b1 : h1b0;
      half_t* h2r = (((s - 1) & 1)) ? h2b1 : h2b0;
      half_t* h2w = ((s & 1))       ? h2b1 : h2b0;
      tick(false, true, false, false, 0, h1r, h1b0, h2r, h2w);
      groupbar(P.flags, rb, wg, ++bid);
    }
  }
  outrow((((TSTEPS + 7) & 1)) ? h2b1 : h2b0, TSTEPS + 7);
}

extern "C" void kernel_launch(void* const* d_in, const int* in_sizes, int n_in,
                              void* d_out, int out_size, void* d_ws, size_t ws_size,
                              hipStream_t stream) {
  Params P;
  P.input_t = (const float*)d_in[0];
  // d_in[1] = y : only its shape (T) matters; T hardcoded 512
  P.W_ih1 = (const float*)d_in[2];  P.b_ih1 = (const float*)d_in[3];
  P.W_hh1 = (const float*)d_in[4];  P.b_hh1 = (const float*)d_in[5];
  P.W_ih2 = (const float*)d_in[6];  P.b_ih2 = (const float*)d_in[7];
  P.W_hh2 = (const float*)d_in[8];  P.b_hh2 = (const float*)d_in[9];
  P.W_lin = (const float*)d_in[10]; P.b_lin = (const float*)d_in[11];
  P.out   = (float*)d_out;

  char* ws = (char*)d_ws;
  P.flags   = (unsigned*)(ws + 2048);                                 // 256*128 B = 32 KB
  P.outfeed = (float*)(ws + 256);
  P.h1buf   = (half_t*)(ws + 2048 + 32768);                           // [2][2][B][H]
  P.h2buf   = (half_t*)(ws + 2048 + 32768 + 4 * (size_t)HPLANE * sizeof(half_t));
  const size_t need = 2048 + 32768 + 8 * (size_t)HPLANE * sizeof(half_t);  // ~2.1 MB

  (void)hipMemsetAsync(d_ws, 0, need, stream);  // zero flags + outfeed + h buffers

  // PLAIN launch: grid == 256 CUs, 1 block/CU by resources => all resident.
  lstm_fused<<<dim3(WGS), dim3(NTHR), 0, stream>>>(P);
}